// Round 1
// baseline (780.797 us; speedup 1.0000x reference)
//
#include <hip/hip_runtime.h>

#define IN_DIM 128
#define OUT_DIM 64

// ---------- helpers: monotone float<->uint mapping for atomic max ----------
__device__ __forceinline__ unsigned fmap(float f) {
    unsigned b = __float_as_uint(f);
    return (b & 0x80000000u) ? ~b : (b | 0x80000000u);
}
__device__ __forceinline__ float funmap(unsigned u) {
    unsigned b = (u & 0x80000000u) ? (u & 0x7FFFFFFFu) : ~u;
    return __uint_as_float(b);
}

// ---------- kernel P: weight products ----------
// W1 = W_fc @ W_edge[0:64,:]   (128x64)
// W2 = W_fc @ W_edge[64:128,:] (128x64)
// wa_s = W_fc @ W_attn[0:64]   (128)
// wa_d = W_fc @ W_attn[64:128] (128)
__global__ void precompute_weights(const float* __restrict__ W_fc,
                                   const float* __restrict__ W_attn,
                                   const float* __restrict__ W_edge,
                                   float* __restrict__ W1, float* __restrict__ W2,
                                   float* __restrict__ wa_s, float* __restrict__ wa_d) {
    int k = blockIdx.x;    // 0..127 (row of W_fc)
    int j = threadIdx.x;   // 0..63  (col)
    __shared__ float row[64];
    row[j] = W_fc[k * 64 + j];
    __syncthreads();
    float s1 = 0.f, s2 = 0.f;
    #pragma unroll 8
    for (int m = 0; m < 64; ++m) {
        float w = row[m];
        s1 = fmaf(w, W_edge[m * 64 + j], s1);
        s2 = fmaf(w, W_edge[(64 + m) * 64 + j], s2);
    }
    W1[k * 64 + j] = s1;
    W2[k * 64 + j] = s2;
    float v1 = row[j] * W_attn[j];
    float v2 = row[j] * W_attn[64 + j];
    #pragma unroll
    for (int off = 32; off; off >>= 1) {
        v1 += __shfl_xor(v1, off);
        v2 += __shfl_xor(v2, off);
    }
    if (j == 0) { wa_s[k] = v1; wa_d[k] = v2; }
}

// ---------- kernel A: node-level GEMM ----------
// z  = h @ W_fc; es = h @ W1; ed = h @ W2; as = h @ wa_s... (as/ad via wave reduce on z)
__global__ __launch_bounds__(256) void node_gemm(
    const float* __restrict__ h,
    const float* __restrict__ W_fc, const float* __restrict__ W1,
    const float* __restrict__ W2, const float* __restrict__ W_attn,
    float* __restrict__ z, float* __restrict__ es, float* __restrict__ ed,
    float* __restrict__ as_, float* __restrict__ ad_, int N)
{
    __shared__ float4 hs4[64][32];   // 64 nodes x 128 f32
    const int tid = threadIdx.x;
    const int c = tid & 63;          // output column (lane)
    const int w = tid >> 6;          // wave id 0..3
    const int n0 = blockIdx.x * 64;

    // stage 64 h-rows (coalesced float4)
    {
        const float4* hg = (const float4*)(h + (size_t)n0 * IN_DIM);
        float4* hl = &hs4[0][0];
        for (int idx = tid; idx < 64 * 32; idx += 256) {
            int node = idx >> 5;
            float4 v = make_float4(0.f, 0.f, 0.f, 0.f);
            if (n0 + node < N) v = hg[idx];
            hl[idx] = v;
        }
    }
    __syncthreads();

    float accz[16], acce[16], accd[16];
    #pragma unroll
    for (int i = 0; i < 16; ++i) { accz[i] = 0.f; acce[i] = 0.f; accd[i] = 0.f; }

    for (int k4 = 0; k4 < 32; ++k4) {
        const int kb = k4 * 4;
        float wf0 = W_fc[(kb + 0) * 64 + c], wf1 = W_fc[(kb + 1) * 64 + c];
        float wf2 = W_fc[(kb + 2) * 64 + c], wf3 = W_fc[(kb + 3) * 64 + c];
        float e0 = W1[(kb + 0) * 64 + c], e1 = W1[(kb + 1) * 64 + c];
        float e2 = W1[(kb + 2) * 64 + c], e3 = W1[(kb + 3) * 64 + c];
        float d0 = W2[(kb + 0) * 64 + c], d1 = W2[(kb + 1) * 64 + c];
        float d2 = W2[(kb + 2) * 64 + c], d3 = W2[(kb + 3) * 64 + c];
        #pragma unroll
        for (int i = 0; i < 16; ++i) {
            float4 hv = hs4[w * 16 + i][k4];   // wave-uniform -> LDS broadcast
            accz[i] = fmaf(hv.x, wf0, accz[i]); accz[i] = fmaf(hv.y, wf1, accz[i]);
            accz[i] = fmaf(hv.z, wf2, accz[i]); accz[i] = fmaf(hv.w, wf3, accz[i]);
            acce[i] = fmaf(hv.x, e0, acce[i]);  acce[i] = fmaf(hv.y, e1, acce[i]);
            acce[i] = fmaf(hv.z, e2, acce[i]);  acce[i] = fmaf(hv.w, e3, acce[i]);
            accd[i] = fmaf(hv.x, d0, accd[i]);  accd[i] = fmaf(hv.y, d1, accd[i]);
            accd[i] = fmaf(hv.z, d2, accd[i]);  accd[i] = fmaf(hv.w, d3, accd[i]);
        }
    }

    const float wa = W_attn[c], wb = W_attn[64 + c];
    #pragma unroll
    for (int i = 0; i < 16; ++i) {
        const int n = n0 + w * 16 + i;
        if (n < N) {
            z [(size_t)n * 64 + c] = accz[i];
            es[(size_t)n * 64 + c] = acce[i];
            ed[(size_t)n * 64 + c] = accd[i];
        }
        float v1 = accz[i] * wa;
        float v2 = accz[i] * wb;
        #pragma unroll
        for (int off = 32; off; off >>= 1) {
            v1 += __shfl_xor(v1, off);
            v2 += __shfl_xor(v2, off);
        }
        if (c == 0 && n < N) { as_[n] = v1; ad_[n] = v2; }
    }
}

// ---------- kernel B: per-edge logits, segment max, degree ----------
__global__ void edge_pass1(const int* __restrict__ src, const int* __restrict__ dst,
                           const float* __restrict__ as_, const float* __restrict__ ad_,
                           float* __restrict__ a_e, unsigned* __restrict__ amax_u,
                           unsigned* __restrict__ deg, int E) {
    int i = blockIdx.x * blockDim.x + threadIdx.x;
    if (i >= E) return;
    int s = src[i], d = dst[i];
    float a = as_[s] + ad_[d];
    a_e[i] = a;
    atomicMax(&amax_u[d], fmap(a));
    atomicAdd(&deg[d], 1u);
}

// ---------- kernel C: exp + denominator ----------
__global__ void edge_pass2(const int* __restrict__ dst, const float* __restrict__ a_e,
                           const unsigned* __restrict__ amax_u,
                           float* __restrict__ w_e, float* __restrict__ denom, int E) {
    int i = blockIdx.x * blockDim.x + threadIdx.x;
    if (i >= E) return;
    int d = dst[i];
    float m = funmap(amax_u[d]);
    float w = expf(a_e[i] - m);
    w_e[i] = w;
    atomicAdd(&denom[d], w);
}

// ---------- kernel D: weighted scatter (64 lanes = 64 features per edge) ----------
__global__ __launch_bounds__(256) void edge_scatter(
    const int* __restrict__ src, const int* __restrict__ dst,
    const float* __restrict__ w_e, const float* __restrict__ denom,
    const float* __restrict__ z, const float* __restrict__ es,
    float* __restrict__ out, int E)
{
    const int lane = threadIdx.x & 63;
    const int estart = blockIdx.x * 4 + (threadIdx.x >> 6);
    const int estride = gridDim.x * 4;
    for (int i = estart; i < E; i += estride) {
        int s = src[i], d = dst[i];
        float alpha = w_e[i] / denom[d];
        float v = fmaf(alpha, z[(size_t)s * 64 + lane], es[(size_t)s * 64 + lane]);
        atomicAdd(&out[(size_t)d * 64 + lane], v);
    }
}

// ---------- kernel E: add degree-weighted ed ----------
__global__ void add_ed(const unsigned* __restrict__ deg, const float* __restrict__ ed,
                       float* __restrict__ out, int total) {
    int idx = blockIdx.x * blockDim.x + threadIdx.x;
    if (idx >= total) return;
    int n = idx >> 6;
    out[idx] += (float)deg[n] * ed[idx];
}

extern "C" void kernel_launch(void* const* d_in, const int* in_sizes, int n_in,
                              void* d_out, int out_size, void* d_ws, size_t ws_size,
                              hipStream_t stream) {
    const float* h      = (const float*)d_in[0];
    const float* W_fc   = (const float*)d_in[1];
    const float* W_attn = (const float*)d_in[2];
    const float* W_edge = (const float*)d_in[3];
    const int*   src    = (const int*)d_in[4];
    const int*   dst    = (const int*)d_in[5];
    float* out = (float*)d_out;

    const int N = in_sizes[0] / IN_DIM;       // 100000
    const int E = in_sizes[4];                // 1600000

    // workspace carve-out (256B aligned regions)
    char* p = (char*)d_ws;
    auto alloc = [&](size_t bytes) -> void* {
        void* r = (void*)p;
        p += (bytes + 255) & ~(size_t)255;
        return r;
    };
    float*    z      = (float*)alloc((size_t)N * 64 * 4);
    float*    es     = (float*)alloc((size_t)N * 64 * 4);
    float*    ed     = (float*)alloc((size_t)N * 64 * 4);
    float*    as_    = (float*)alloc((size_t)N * 4);
    float*    ad_    = (float*)alloc((size_t)N * 4);
    unsigned* amax_u = (unsigned*)alloc((size_t)N * 4);
    float*    denom  = (float*)alloc((size_t)N * 4);
    unsigned* deg    = (unsigned*)alloc((size_t)N * 4);
    float*    a_e    = (float*)alloc((size_t)E * 4);
    float*    w_e    = (float*)alloc((size_t)E * 4);
    float*    W1     = (float*)alloc(128 * 64 * 4);
    float*    W2     = (float*)alloc(128 * 64 * 4);
    float*    wa_s   = (float*)alloc(128 * 4);
    float*    wa_d   = (float*)alloc(128 * 4);

    // zero-init accumulators (ws/out are poisoned with 0xAA before every call)
    hipMemsetAsync(out, 0, (size_t)out_size * 4, stream);
    hipMemsetAsync(amax_u, 0, (size_t)N * 4, stream);   // 0 == mapped(-NaN) < any finite
    hipMemsetAsync(denom, 0, (size_t)N * 4, stream);
    hipMemsetAsync(deg, 0, (size_t)N * 4, stream);

    precompute_weights<<<128, 64, 0, stream>>>(W_fc, W_attn, W_edge, W1, W2, wa_s, wa_d);

    int blocksA = (N + 63) / 64;
    node_gemm<<<blocksA, 256, 0, stream>>>(h, W_fc, W1, W2, W_attn, z, es, ed, as_, ad_, N);

    int blocksE = (E + 255) / 256;
    edge_pass1<<<blocksE, 256, 0, stream>>>(src, dst, as_, ad_, a_e, amax_u, deg, E);
    edge_pass2<<<blocksE, 256, 0, stream>>>(dst, a_e, amax_u, w_e, denom, E);

    edge_scatter<<<2048, 256, 0, stream>>>(src, dst, w_e, denom, z, es, out, E);

    int totalOut = N * 64;
    add_ed<<<(totalOut + 255) / 256, 256, 0, stream>>>(deg, ed, out, totalOut);
}

// Round 2
// 499.269 us; speedup vs baseline: 1.5639x; 1.5639x over previous
//
#include <hip/hip_runtime.h>

#define IN_DIM 128
#define OUT_DIM 64

// ---------- kernel P: weight products ----------
// W1 = W_fc @ W_edge[0:64,:]   (128x64)
// W2 = W_fc @ W_edge[64:128,:] (128x64)
__global__ void precompute_weights(const float* __restrict__ W_fc,
                                   const float* __restrict__ W_edge,
                                   float* __restrict__ W1, float* __restrict__ W2) {
    int k = blockIdx.x;    // 0..127 (row of W_fc)
    int j = threadIdx.x;   // 0..63  (col)
    __shared__ float row[64];
    row[j] = W_fc[k * 64 + j];
    __syncthreads();
    float s1 = 0.f, s2 = 0.f;
    #pragma unroll 8
    for (int m = 0; m < 64; ++m) {
        float w = row[m];
        s1 = fmaf(w, W_edge[m * 64 + j], s1);
        s2 = fmaf(w, W_edge[(64 + m) * 64 + j], s2);
    }
    W1[k * 64 + j] = s1;
    W2[k * 64 + j] = s2;
}

// ---------- kernel A: node-level GEMM ----------
// zes[n][2c]=z, zes[n][2c+1]=es (interleaved for 512B/row edge gathers)
// ed = h @ W2; as_/ad_ = z . W_attn halves (wave reduce)
__global__ __launch_bounds__(256) void node_gemm(
    const float* __restrict__ h,
    const float* __restrict__ W_fc, const float* __restrict__ W1,
    const float* __restrict__ W2, const float* __restrict__ W_attn,
    float* __restrict__ zes, float* __restrict__ ed,
    float* __restrict__ as_, float* __restrict__ ad_, int N)
{
    __shared__ float4 hs4[64][32];   // 64 nodes x 128 f32
    const int tid = threadIdx.x;
    const int c = tid & 63;          // output column (lane)
    const int w = tid >> 6;          // wave id 0..3
    const int n0 = blockIdx.x * 64;

    {
        const float4* hg = (const float4*)(h + (size_t)n0 * IN_DIM);
        float4* hl = &hs4[0][0];
        for (int idx = tid; idx < 64 * 32; idx += 256) {
            int node = idx >> 5;
            float4 v = make_float4(0.f, 0.f, 0.f, 0.f);
            if (n0 + node < N) v = hg[idx];
            hl[idx] = v;
        }
    }
    __syncthreads();

    float accz[16], acce[16], accd[16];
    #pragma unroll
    for (int i = 0; i < 16; ++i) { accz[i] = 0.f; acce[i] = 0.f; accd[i] = 0.f; }

    for (int k4 = 0; k4 < 32; ++k4) {
        const int kb = k4 * 4;
        float wf0 = W_fc[(kb + 0) * 64 + c], wf1 = W_fc[(kb + 1) * 64 + c];
        float wf2 = W_fc[(kb + 2) * 64 + c], wf3 = W_fc[(kb + 3) * 64 + c];
        float e0 = W1[(kb + 0) * 64 + c], e1 = W1[(kb + 1) * 64 + c];
        float e2 = W1[(kb + 2) * 64 + c], e3 = W1[(kb + 3) * 64 + c];
        float d0 = W2[(kb + 0) * 64 + c], d1 = W2[(kb + 1) * 64 + c];
        float d2 = W2[(kb + 2) * 64 + c], d3 = W2[(kb + 3) * 64 + c];
        #pragma unroll
        for (int i = 0; i < 16; ++i) {
            float4 hv = hs4[w * 16 + i][k4];   // wave-uniform -> LDS broadcast
            accz[i] = fmaf(hv.x, wf0, accz[i]); accz[i] = fmaf(hv.y, wf1, accz[i]);
            accz[i] = fmaf(hv.z, wf2, accz[i]); accz[i] = fmaf(hv.w, wf3, accz[i]);
            acce[i] = fmaf(hv.x, e0, acce[i]);  acce[i] = fmaf(hv.y, e1, acce[i]);
            acce[i] = fmaf(hv.z, e2, acce[i]);  acce[i] = fmaf(hv.w, e3, acce[i]);
            accd[i] = fmaf(hv.x, d0, accd[i]);  accd[i] = fmaf(hv.y, d1, accd[i]);
            accd[i] = fmaf(hv.z, d2, accd[i]);  accd[i] = fmaf(hv.w, d3, accd[i]);
        }
    }

    const float wa = W_attn[c], wb = W_attn[64 + c];
    #pragma unroll
    for (int i = 0; i < 16; ++i) {
        const int n = n0 + w * 16 + i;
        if (n < N) {
            *(float2*)&zes[(size_t)n * 128 + 2 * c] = make_float2(accz[i], acce[i]);
            ed[(size_t)n * 64 + c] = accd[i];
        }
        float v1 = accz[i] * wa;
        float v2 = accz[i] * wb;
        #pragma unroll
        for (int off = 32; off; off >>= 1) {
            v1 += __shfl_xor(v1, off);
            v2 += __shfl_xor(v2, off);
        }
        if (c == 0 && n < N) { as_[n] = v1; ad_[n] = v2; }
    }
}

// ---------- CSR build: count, scan, bin ----------
__global__ void count_deg(const int* __restrict__ dst, unsigned* __restrict__ deg, int E) {
    int i = blockIdx.x * blockDim.x + threadIdx.x;
    if (i < E) atomicAdd(&deg[dst[i]], 1u);
}

__global__ void scan_partial(const unsigned* __restrict__ deg, unsigned* __restrict__ part, int N) {
    __shared__ unsigned s[256];
    int t = threadIdx.x;
    int i = blockIdx.x * 256 + t;
    unsigned v = (i < N) ? deg[i] : 0u;
    s[t] = v; __syncthreads();
    for (int off = 128; off; off >>= 1) {
        if (t < off) s[t] += s[t + off];
        __syncthreads();
    }
    if (t == 0) part[blockIdx.x] = s[0];
}

// single block: in-place exclusive scan of nb block sums (sequential tiles of 256)
__global__ void scan_blocksums(unsigned* part, int nb) {
    __shared__ unsigned s[256];
    __shared__ unsigned base_s;
    int t = threadIdx.x;
    if (t == 0) base_s = 0;
    __syncthreads();
    for (int start = 0; start < nb; start += 256) {
        int i = start + t;
        unsigned v = (i < nb) ? part[i] : 0u;
        s[t] = v; __syncthreads();
        for (int off = 1; off < 256; off <<= 1) {
            unsigned add = (t >= off) ? s[t - off] : 0u;
            __syncthreads();
            s[t] += add;
            __syncthreads();
        }
        unsigned incl = s[t];
        unsigned base = base_s;
        if (i < nb) part[i] = base + incl - v;   // exclusive
        __syncthreads();
        if (t == 255) base_s = base + incl;      // running total
        __syncthreads();
    }
}

__global__ void scan_final(const unsigned* __restrict__ deg, const unsigned* __restrict__ part,
                           unsigned* __restrict__ offs, int N) {
    __shared__ unsigned s[256];
    int t = threadIdx.x;
    int i = blockIdx.x * 256 + t;
    unsigned v = (i < N) ? deg[i] : 0u;
    s[t] = v; __syncthreads();
    for (int off = 1; off < 256; off <<= 1) {
        unsigned add = (t >= off) ? s[t - off] : 0u;
        __syncthreads();
        s[t] += add;
        __syncthreads();
    }
    unsigned excl = s[t] - v + part[blockIdx.x];
    if (i < N) {
        offs[i] = excl;
        if (i == N - 1) offs[N] = excl + v;
    }
}

__global__ void bin_edges(const int* __restrict__ src, const int* __restrict__ dst,
                          const unsigned* __restrict__ offs, unsigned* __restrict__ cursor,
                          int* __restrict__ src_sorted, int E) {
    int i = blockIdx.x * blockDim.x + threadIdx.x;
    if (i >= E) return;
    int d = dst[i];
    unsigned pos = offs[d] + atomicAdd(&cursor[d], 1u);
    src_sorted[pos] = src[i];
}

// ---------- kernel G: per-dst gather (one wave per node) ----------
__global__ __launch_bounds__(256) void gather_nodes(
    const int* __restrict__ src_sorted, const unsigned* __restrict__ offs,
    const float* __restrict__ as_, const float* __restrict__ ad_,
    const float* __restrict__ zes, const float* __restrict__ ed,
    float* __restrict__ out, int N)
{
    const int lane = threadIdx.x & 63;
    const int d = blockIdx.x * 4 + (threadIdx.x >> 6);
    if (d >= N) return;
    const unsigned o0 = offs[d], o1 = offs[d + 1];
    const int deg = (int)(o1 - o0);
    const float ad_d = ad_[d];

    // phase A: online softmax (max + sum of exp), no atomics
    float m = -INFINITY, l = 0.f;
    for (unsigned o = o0; o < o1; o += 64) {
        int rem = min(64, (int)(o1 - o));
        float a = -INFINITY;
        if (lane < rem) a = as_[src_sorted[o + lane]] + ad_d;
        float cm = a;
        #pragma unroll
        for (int off = 32; off; off >>= 1) cm = fmaxf(cm, __shfl_xor(cm, off));
        float mn = fmaxf(m, cm);
        float w = (lane < rem) ? expf(a - mn) : 0.f;
        float cs = w;
        #pragma unroll
        for (int off = 32; off; off >>= 1) cs += __shfl_xor(cs, off);
        l = l * expf(m - mn) + cs;
        m = mn;
    }
    const float inv_denom = (l > 0.f) ? 1.f / l : 0.f;

    // phase B: weighted gather, 512B coalesced row per edge
    float acc = 0.f;
    for (unsigned o = o0; o < o1; o += 64) {
        int rem = min(64, (int)(o1 - o));
        int s = 0; float w = 0.f;
        if (lane < rem) {
            s = src_sorted[o + lane];
            w = expf(as_[s] + ad_d - m) * inv_denom;
        }
        for (int j = 0; j < rem; ++j) {
            int sj = __builtin_amdgcn_readlane(s, j);                               // uniform
            float wj = __uint_as_float(__builtin_amdgcn_readlane(__float_as_uint(w), j));
            float2 v = *(const float2*)&zes[(size_t)sj * 128 + 2 * lane];
            acc = fmaf(wj, v.x, acc) + v.y;
        }
    }
    acc = fmaf((float)deg, ed[(size_t)d * 64 + lane], acc);
    out[(size_t)d * 64 + lane] = acc;
}

extern "C" void kernel_launch(void* const* d_in, const int* in_sizes, int n_in,
                              void* d_out, int out_size, void* d_ws, size_t ws_size,
                              hipStream_t stream) {
    const float* h      = (const float*)d_in[0];
    const float* W_fc   = (const float*)d_in[1];
    const float* W_attn = (const float*)d_in[2];
    const float* W_edge = (const float*)d_in[3];
    const int*   src    = (const int*)d_in[4];
    const int*   dst    = (const int*)d_in[5];
    float* out = (float*)d_out;

    const int N = in_sizes[0] / IN_DIM;       // 100000
    const int E = in_sizes[4];                // 1600000

    char* p = (char*)d_ws;
    auto alloc = [&](size_t bytes) -> void* {
        void* r = (void*)p;
        p += (bytes + 255) & ~(size_t)255;
        return r;
    };
    float*    zes    = (float*)alloc((size_t)N * 128 * 4);
    float*    ed     = (float*)alloc((size_t)N * 64 * 4);
    float*    as_    = (float*)alloc((size_t)N * 4);
    float*    ad_    = (float*)alloc((size_t)N * 4);
    unsigned* deg    = (unsigned*)alloc((size_t)N * 4);
    unsigned* cursor = (unsigned*)alloc((size_t)N * 4);
    unsigned* offs   = (unsigned*)alloc((size_t)(N + 1) * 4);
    unsigned* part   = (unsigned*)alloc((size_t)((N + 255) / 256) * 4);
    int*      src_s  = (int*)alloc((size_t)E * 4);
    float*    W1     = (float*)alloc(128 * 64 * 4);
    float*    W2     = (float*)alloc(128 * 64 * 4);

    hipMemsetAsync(deg, 0, (size_t)N * 4, stream);
    hipMemsetAsync(cursor, 0, (size_t)N * 4, stream);

    precompute_weights<<<128, 64, 0, stream>>>(W_fc, W_edge, W1, W2);

    int blocksA = (N + 63) / 64;
    node_gemm<<<blocksA, 256, 0, stream>>>(h, W_fc, W1, W2, W_attn, zes, ed, as_, ad_, N);

    int blocksE = (E + 255) / 256;
    count_deg<<<blocksE, 256, 0, stream>>>(dst, deg, E);

    int nb = (N + 255) / 256;
    scan_partial<<<nb, 256, 0, stream>>>(deg, part, N);
    scan_blocksums<<<1, 256, 0, stream>>>(part, nb);
    scan_final<<<nb, 256, 0, stream>>>(deg, part, offs, N);

    bin_edges<<<blocksE, 256, 0, stream>>>(src, dst, offs, cursor, src_s, E);

    gather_nodes<<<(N + 3) / 4, 256, 0, stream>>>(src_s, offs, as_, ad_, zes, ed, out, N);
}

// Round 3
// 460.829 us; speedup vs baseline: 1.6943x; 1.0834x over previous
//
#include <hip/hip_runtime.h>

#define IN_DIM 128
#define OUT_DIM 64

// ---------- bf16 pack/unpack (RNE) ----------
__device__ __forceinline__ unsigned pack_bf16x2(float a, float b) {
    unsigned ua = __float_as_uint(a), ub = __float_as_uint(b);
    ua = (ua + 0x7fffu + ((ua >> 16) & 1u)) >> 16;
    ub = (ub + 0x7fffu + ((ub >> 16) & 1u)) >> 16;
    return ua | (ub << 16);
}

// ---------- kernel P: weight products ----------
// W1 = W_fc @ W_edge[0:64,:]   (128x64)
// W2 = W_fc @ W_edge[64:128,:] (128x64)
__global__ void precompute_weights(const float* __restrict__ W_fc,
                                   const float* __restrict__ W_edge,
                                   float* __restrict__ W1, float* __restrict__ W2) {
    int k = blockIdx.x;    // 0..127 (row of W_fc)
    int j = threadIdx.x;   // 0..63  (col)
    __shared__ float row[64];
    row[j] = W_fc[k * 64 + j];
    __syncthreads();
    float s1 = 0.f, s2 = 0.f;
    #pragma unroll 8
    for (int m = 0; m < 64; ++m) {
        float w = row[m];
        s1 = fmaf(w, W_edge[m * 64 + j], s1);
        s2 = fmaf(w, W_edge[(64 + m) * 64 + j], s2);
    }
    W1[k * 64 + j] = s1;
    W2[k * 64 + j] = s2;
}

// ---------- kernel A: node-level GEMM ----------
// zes[n*64+c] = packed bf16 (z, es); ed = h @ W2 (f32); ws[n] = exp(z . wa_s)
__global__ __launch_bounds__(256) void node_gemm(
    const float* __restrict__ h,
    const float* __restrict__ W_fc, const float* __restrict__ W1,
    const float* __restrict__ W2, const float* __restrict__ W_attn,
    unsigned* __restrict__ zes, float* __restrict__ ed,
    float* __restrict__ ws_, int N)
{
    __shared__ float4 hs4[64][32];   // 64 nodes x 128 f32
    const int tid = threadIdx.x;
    const int c = tid & 63;          // output column (lane)
    const int w = tid >> 6;          // wave id 0..3
    const int n0 = blockIdx.x * 64;

    {
        const float4* hg = (const float4*)(h + (size_t)n0 * IN_DIM);
        float4* hl = &hs4[0][0];
        for (int idx = tid; idx < 64 * 32; idx += 256) {
            int node = idx >> 5;
            float4 v = make_float4(0.f, 0.f, 0.f, 0.f);
            if (n0 + node < N) v = hg[idx];
            hl[idx] = v;
        }
    }
    __syncthreads();

    float accz[16], acce[16], accd[16];
    #pragma unroll
    for (int i = 0; i < 16; ++i) { accz[i] = 0.f; acce[i] = 0.f; accd[i] = 0.f; }

    for (int k4 = 0; k4 < 32; ++k4) {
        const int kb = k4 * 4;
        float wf0 = W_fc[(kb + 0) * 64 + c], wf1 = W_fc[(kb + 1) * 64 + c];
        float wf2 = W_fc[(kb + 2) * 64 + c], wf3 = W_fc[(kb + 3) * 64 + c];
        float e0 = W1[(kb + 0) * 64 + c], e1 = W1[(kb + 1) * 64 + c];
        float e2 = W1[(kb + 2) * 64 + c], e3 = W1[(kb + 3) * 64 + c];
        float d0 = W2[(kb + 0) * 64 + c], d1 = W2[(kb + 1) * 64 + c];
        float d2 = W2[(kb + 2) * 64 + c], d3 = W2[(kb + 3) * 64 + c];
        #pragma unroll
        for (int i = 0; i < 16; ++i) {
            float4 hv = hs4[w * 16 + i][k4];   // wave-uniform -> LDS broadcast
            accz[i] = fmaf(hv.x, wf0, accz[i]); accz[i] = fmaf(hv.y, wf1, accz[i]);
            accz[i] = fmaf(hv.z, wf2, accz[i]); accz[i] = fmaf(hv.w, wf3, accz[i]);
            acce[i] = fmaf(hv.x, e0, acce[i]);  acce[i] = fmaf(hv.y, e1, acce[i]);
            acce[i] = fmaf(hv.z, e2, acce[i]);  acce[i] = fmaf(hv.w, e3, acce[i]);
            accd[i] = fmaf(hv.x, d0, accd[i]);  accd[i] = fmaf(hv.y, d1, accd[i]);
            accd[i] = fmaf(hv.z, d2, accd[i]);  accd[i] = fmaf(hv.w, d3, accd[i]);
        }
    }

    const float wa = W_attn[c];
    #pragma unroll
    for (int i = 0; i < 16; ++i) {
        const int n = n0 + w * 16 + i;
        if (n < N) {
            zes[(size_t)n * 64 + c] = pack_bf16x2(accz[i], acce[i]);
            ed[(size_t)n * 64 + c] = accd[i];
        }
        float v1 = accz[i] * wa;
        #pragma unroll
        for (int off = 32; off; off >>= 1) v1 += __shfl_xor(v1, off);
        if (c == 0 && n < N) ws_[n] = expf(v1);
    }
}

// ---------- CSR build: count, scan, bin ----------
__global__ void count_deg(const int* __restrict__ dst, unsigned* __restrict__ deg, int E) {
    int i = blockIdx.x * blockDim.x + threadIdx.x;
    if (i < E) atomicAdd(&deg[dst[i]], 1u);
}

__global__ void scan_partial(const unsigned* __restrict__ deg, unsigned* __restrict__ part, int N) {
    __shared__ unsigned s[256];
    int t = threadIdx.x;
    int i = blockIdx.x * 256 + t;
    unsigned v = (i < N) ? deg[i] : 0u;
    s[t] = v; __syncthreads();
    for (int off = 128; off; off >>= 1) {
        if (t < off) s[t] += s[t + off];
        __syncthreads();
    }
    if (t == 0) part[blockIdx.x] = s[0];
}

__global__ void scan_blocksums(unsigned* part, int nb) {
    __shared__ unsigned s[256];
    __shared__ unsigned base_s;
    int t = threadIdx.x;
    if (t == 0) base_s = 0;
    __syncthreads();
    for (int start = 0; start < nb; start += 256) {
        int i = start + t;
        unsigned v = (i < nb) ? part[i] : 0u;
        s[t] = v; __syncthreads();
        for (int off = 1; off < 256; off <<= 1) {
            unsigned add = (t >= off) ? s[t - off] : 0u;
            __syncthreads();
            s[t] += add;
            __syncthreads();
        }
        unsigned incl = s[t];
        unsigned base = base_s;
        if (i < nb) part[i] = base + incl - v;   // exclusive
        __syncthreads();
        if (t == 255) base_s = base + incl;      // running total
        __syncthreads();
    }
}

__global__ void scan_final(const unsigned* __restrict__ deg, const unsigned* __restrict__ part,
                           unsigned* __restrict__ offs, int N) {
    __shared__ unsigned s[256];
    int t = threadIdx.x;
    int i = blockIdx.x * 256 + t;
    unsigned v = (i < N) ? deg[i] : 0u;
    s[t] = v; __syncthreads();
    for (int off = 1; off < 256; off <<= 1) {
        unsigned add = (t >= off) ? s[t - off] : 0u;
        __syncthreads();
        s[t] += add;
        __syncthreads();
    }
    unsigned excl = s[t] - v + part[blockIdx.x];
    if (i < N) {
        offs[i] = excl;
        if (i == N - 1) offs[N] = excl + v;
    }
}

__global__ void bin_edges(const int* __restrict__ src, const int* __restrict__ dst,
                          const unsigned* __restrict__ offs, unsigned* __restrict__ cursor,
                          int* __restrict__ src_sorted, int E) {
    int i = blockIdx.x * blockDim.x + threadIdx.x;
    if (i >= E) return;
    int d = dst[i];
    unsigned pos = offs[d] + atomicAdd(&cursor[d], 1u);
    src_sorted[pos] = src[i];
}

// ---------- kernel G: per-dst gather, single pass (one wave per node) ----------
// out[d] = (sum_s w_s * z[s]) / (sum_s w_s) + sum_s es[s] + deg * ed[d]
__global__ __launch_bounds__(256) void gather_nodes(
    const int* __restrict__ src_sorted, const unsigned* __restrict__ offs,
    const float* __restrict__ ws_, const unsigned* __restrict__ zes,
    const float* __restrict__ ed, float* __restrict__ out, int N)
{
    const int lane = threadIdx.x & 63;
    const int d = blockIdx.x * 4 + (threadIdx.x >> 6);
    if (d >= N) return;
    const unsigned o0 = offs[d], o1 = offs[d + 1];
    const int deg = (int)(o1 - o0);

    float accz = 0.f, acce = 0.f, l = 0.f;
    for (unsigned o = o0; o < o1; o += 64) {
        int rem = min(64, (int)(o1 - o));
        int s = 0; float w = 0.f;
        if (lane < rem) {
            s = src_sorted[o + lane];
            w = ws_[s];
        }
        for (int j = 0; j < rem; ++j) {
            int sj = __builtin_amdgcn_readlane(s, j);
            float wj = __uint_as_float(__builtin_amdgcn_readlane(__float_as_uint(w), j));
            unsigned u = zes[(size_t)sj * 64 + lane];            // 256B coalesced row
            float zz = __uint_as_float(u << 16);                 // bf16 z
            float ee = __uint_as_float(u & 0xffff0000u);         // bf16 es
            accz = fmaf(wj, zz, accz);
            acce += ee;
            l += wj;
        }
    }
    const float inv = (l > 0.f) ? 1.f / l : 0.f;
    float r = fmaf(accz, inv, acce);
    r = fmaf((float)deg, ed[(size_t)d * 64 + lane], r);
    out[(size_t)d * 64 + lane] = r;
}

extern "C" void kernel_launch(void* const* d_in, const int* in_sizes, int n_in,
                              void* d_out, int out_size, void* d_ws, size_t ws_size,
                              hipStream_t stream) {
    const float* h      = (const float*)d_in[0];
    const float* W_fc   = (const float*)d_in[1];
    const float* W_attn = (const float*)d_in[2];
    const float* W_edge = (const float*)d_in[3];
    const int*   src    = (const int*)d_in[4];
    const int*   dst    = (const int*)d_in[5];
    float* out = (float*)d_out;

    const int N = in_sizes[0] / IN_DIM;       // 100000
    const int E = in_sizes[4];                // 1600000

    char* p = (char*)d_ws;
    auto alloc = [&](size_t bytes) -> void* {
        void* r = (void*)p;
        p += (bytes + 255) & ~(size_t)255;
        return r;
    };
    unsigned* zes    = (unsigned*)alloc((size_t)N * 64 * 4);   // packed bf16 (z, es)
    float*    ed     = (float*)alloc((size_t)N * 64 * 4);
    float*    ws_    = (float*)alloc((size_t)N * 4);
    unsigned* deg    = (unsigned*)alloc((size_t)N * 4);
    unsigned* cursor = (unsigned*)alloc((size_t)N * 4);
    unsigned* offs   = (unsigned*)alloc((size_t)(N + 1) * 4);
    unsigned* part   = (unsigned*)alloc((size_t)((N + 255) / 256) * 4);
    int*      src_s  = (int*)alloc((size_t)E * 4);
    float*    W1     = (float*)alloc(128 * 64 * 4);
    float*    W2     = (float*)alloc(128 * 64 * 4);

    hipMemsetAsync(deg, 0, (size_t)N * 4, stream);
    hipMemsetAsync(cursor, 0, (size_t)N * 4, stream);

    precompute_weights<<<128, 64, 0, stream>>>(W_fc, W_edge, W1, W2);

    int blocksA = (N + 63) / 64;
    node_gemm<<<blocksA, 256, 0, stream>>>(h, W_fc, W1, W2, W_attn, zes, ed, ws_, N);

    int blocksE = (E + 255) / 256;
    count_deg<<<blocksE, 256, 0, stream>>>(dst, deg, E);

    int nb = (N + 255) / 256;
    scan_partial<<<nb, 256, 0, stream>>>(deg, part, N);
    scan_blocksums<<<1, 256, 0, stream>>>(part, nb);
    scan_final<<<nb, 256, 0, stream>>>(deg, part, offs, N);

    bin_edges<<<blocksE, 256, 0, stream>>>(src, dst, offs, cursor, src_s, E);

    gather_nodes<<<(N + 3) / 4, 256, 0, stream>>>(src_s, offs, ws_, zes, ed, out, N);
}

// Round 4
// 353.246 us; speedup vs baseline: 2.2103x; 1.3046x over previous
//
#include <hip/hip_runtime.h>

#define IN_DIM 128
#define OUT_DIM 64

typedef __attribute__((ext_vector_type(8))) short short8;
typedef __attribute__((ext_vector_type(4))) float f32x4;

// ---------- bf16 pack (RNE) ----------
__device__ __forceinline__ unsigned pack_bf16x2(float a, float b) {
    unsigned ua = __float_as_uint(a), ub = __float_as_uint(b);
    ua = (ua + 0x7fffu + ((ua >> 16) & 1u)) >> 16;
    ub = (ub + 0x7fffu + ((ub >> 16) & 1u)) >> 16;
    return ua | (ub << 16);
}

// ---------- kernel P: weight products ----------
// W1 = W_fc @ W_edge[0:64,:]   (128x64)
// W2 = W_fc @ W_edge[64:128,:] (128x64)
__global__ void precompute_weights(const float* __restrict__ W_fc,
                                   const float* __restrict__ W_edge,
                                   float* __restrict__ W1, float* __restrict__ W2) {
    int k = blockIdx.x;    // 0..127
    int j = threadIdx.x;   // 0..63
    __shared__ float row[64];
    row[j] = W_fc[k * 64 + j];
    __syncthreads();
    float s1 = 0.f, s2 = 0.f;
    #pragma unroll 8
    for (int m = 0; m < 64; ++m) {
        float w = row[m];
        s1 = fmaf(w, W_edge[m * 64 + j], s1);
        s2 = fmaf(w, W_edge[(64 + m) * 64 + j], s2);
    }
    W1[k * 64 + j] = s1;
    W2[k * 64 + j] = s2;
}

// ---------- kernel P2: pack B-fragments for MFMA ----------
// 12 N-tiles (0-3: W_fc -> z, 4-7: W1 -> es, 8-11: W2 -> ed) x 4 K-steps.
// Lane slot layout must match node_gemm's A-frag k-order: k = ks*32 + (lane>>4)*8 + j.
__global__ void pack_bfrags(const float* __restrict__ W_fc, const float* __restrict__ W1,
                            const float* __restrict__ W2, unsigned* __restrict__ bfrag) {
    int slot = blockIdx.x * 256 + threadIdx.x;       // 0..3071
    if (slot >= 12 * 4 * 64) return;
    int lane = slot & 63;
    int ks = (slot >> 6) & 3;
    int t = slot >> 8;                                // 0..11
    int grp = t >> 2;
    int col = (t & 3) * 16 + (lane & 15);
    int kbase = ks * 32 + (lane >> 4) * 8;
    const float* W = (grp == 0) ? W_fc : ((grp == 1) ? W1 : W2);
    unsigned o0 = pack_bf16x2(W[(kbase + 0) * 64 + col], W[(kbase + 1) * 64 + col]);
    unsigned o1 = pack_bf16x2(W[(kbase + 2) * 64 + col], W[(kbase + 3) * 64 + col]);
    unsigned o2 = pack_bf16x2(W[(kbase + 4) * 64 + col], W[(kbase + 5) * 64 + col]);
    unsigned o3 = pack_bf16x2(W[(kbase + 6) * 64 + col], W[(kbase + 7) * 64 + col]);
    ((uint4*)bfrag)[slot] = make_uint4(o0, o1, o2, o3);
}

// ---------- kernel A: MFMA node GEMM ----------
// C = h[64 x 128] @ W[128 x 192] per block; waves own 16-row stripes.
// Outputs: zes (packed bf16 z,es), ed (f32), ws_ = exp(z . W_attn[0:64]).
__global__ __launch_bounds__(256) void node_gemm(
    const float* __restrict__ h, const unsigned* __restrict__ bfrag,
    const float* __restrict__ W_attn,
    unsigned* __restrict__ zes, float* __restrict__ ed,
    float* __restrict__ ws_, int N)
{
    __shared__ uint4 lds4[1024];   // 16 KB: 64 rows x 128 bf16, XOR-swizzled
    char* lds = (char*)lds4;
    const int tid = threadIdx.x;
    const int lane = tid & 63;
    const int w = tid >> 6;
    const int n0 = blockIdx.x * 64;

    // stage h tile as bf16; swizzle byte ^= (row&7)<<4 (G4 fix for 256B rows)
    #pragma unroll
    for (int r = 0; r < 8; ++r) {
        int idx = r * 256 + tid;
        int row = idx >> 5;        // 0..63
        int c4 = idx & 31;         // float4 index within row
        float4 v = make_float4(0.f, 0.f, 0.f, 0.f);
        int n = n0 + row;
        if (n < N) v = *(const float4*)(h + (size_t)n * IN_DIM + c4 * 4);
        int byte = (row << 8) + (c4 << 3);
        byte ^= ((row & 7) << 4);
        *(uint2*)(lds + byte) = make_uint2(pack_bf16x2(v.x, v.y), pack_bf16x2(v.z, v.w));
    }
    __syncthreads();

    const int g = lane >> 4;
    const int c = lane & 15;

    // A-fragments: row = w*16 + (lane&15), k = ks*32 + g*8 + [0..7]
    union U { uint4 u; short8 s; };
    U a[4];
    {
        const int arow = (w << 4) + c;
        #pragma unroll
        for (int ks = 0; ks < 4; ++ks) {
            int byte = (arow << 8) + (ks << 6) + (g << 4);
            byte ^= ((arow & 7) << 4);
            a[ks].u = *(const uint4*)(lds + byte);
        }
    }

    f32x4 acc[12];
    #pragma unroll
    for (int t = 0; t < 12; ++t) acc[t] = (f32x4){0.f, 0.f, 0.f, 0.f};

    const uint4* bf4 = (const uint4*)bfrag;
    #pragma unroll
    for (int t = 0; t < 12; ++t) {
        #pragma unroll
        for (int ks = 0; ks < 4; ++ks) {
            U b; b.u = bf4[(t * 4 + ks) * 64 + lane];
            acc[t] = __builtin_amdgcn_mfma_f32_16x16x32_bf16(a[ks].s, b.s, acc[t], 0, 0, 0);
        }
    }

    // epilogue: C layout col = lane&15, row = w*16 + g*4 + reg (m89-verified)
    const float wa0 = W_attn[c], wa1 = W_attn[16 + c], wa2 = W_attn[32 + c], wa3 = W_attn[48 + c];
    #pragma unroll
    for (int r = 0; r < 4; ++r) {
        const int n = n0 + (w << 4) + (g << 2) + r;
        float part = acc[0][r] * wa0 + acc[1][r] * wa1 + acc[2][r] * wa2 + acc[3][r] * wa3;
        part += __shfl_xor(part, 1);
        part += __shfl_xor(part, 2);
        part += __shfl_xor(part, 4);
        part += __shfl_xor(part, 8);
        if (n < N) {
            #pragma unroll
            for (int t = 0; t < 4; ++t) {
                const int col = t * 16 + c;
                zes[(size_t)n * 64 + col] = pack_bf16x2(acc[t][r], acc[t + 4][r]);
                ed [(size_t)n * 64 + col] = acc[t + 8][r];
            }
            if (c == 0) ws_[n] = expf(part);
        }
    }
}

// ---------- CSR build: count, scan, bin ----------
__global__ void count_deg(const int* __restrict__ dst, unsigned* __restrict__ deg, int E) {
    int i = blockIdx.x * blockDim.x + threadIdx.x;
    if (i < E) atomicAdd(&deg[dst[i]], 1u);
}

__global__ void scan_partial(const unsigned* __restrict__ deg, unsigned* __restrict__ part, int N) {
    __shared__ unsigned s[256];
    int t = threadIdx.x;
    int i = blockIdx.x * 256 + t;
    unsigned v = (i < N) ? deg[i] : 0u;
    s[t] = v; __syncthreads();
    for (int off = 128; off; off >>= 1) {
        if (t < off) s[t] += s[t + off];
        __syncthreads();
    }
    if (t == 0) part[blockIdx.x] = s[0];
}

__global__ void scan_blocksums(unsigned* part, int nb) {
    __shared__ unsigned s[256];
    __shared__ unsigned base_s;
    int t = threadIdx.x;
    if (t == 0) base_s = 0;
    __syncthreads();
    for (int start = 0; start < nb; start += 256) {
        int i = start + t;
        unsigned v = (i < nb) ? part[i] : 0u;
        s[t] = v; __syncthreads();
        for (int off = 1; off < 256; off <<= 1) {
            unsigned add = (t >= off) ? s[t - off] : 0u;
            __syncthreads();
            s[t] += add;
            __syncthreads();
        }
        unsigned incl = s[t];
        unsigned base = base_s;
        if (i < nb) part[i] = base + incl - v;   // exclusive
        __syncthreads();
        if (t == 255) base_s = base + incl;
        __syncthreads();
    }
}

__global__ void scan_final(const unsigned* __restrict__ deg, const unsigned* __restrict__ part,
                           unsigned* __restrict__ offs, int N) {
    __shared__ unsigned s[256];
    int t = threadIdx.x;
    int i = blockIdx.x * 256 + t;
    unsigned v = (i < N) ? deg[i] : 0u;
    s[t] = v; __syncthreads();
    for (int off = 1; off < 256; off <<= 1) {
        unsigned add = (t >= off) ? s[t - off] : 0u;
        __syncthreads();
        s[t] += add;
        __syncthreads();
    }
    unsigned excl = s[t] - v + part[blockIdx.x];
    if (i < N) {
        offs[i] = excl;
        if (i == N - 1) offs[N] = excl + v;
    }
}

__global__ void bin_edges(const int* __restrict__ src, const int* __restrict__ dst,
                          const unsigned* __restrict__ offs, unsigned* __restrict__ cursor,
                          int* __restrict__ src_sorted, int E) {
    int i = blockIdx.x * blockDim.x + threadIdx.x;
    if (i >= E) return;
    int d = dst[i];
    unsigned pos = offs[d] + atomicAdd(&cursor[d], 1u);
    src_sorted[pos] = src[i];
}

// ---------- kernel G: per-dst gather, 4 edges in flight (16 lanes x 16B per edge) ----------
__global__ __launch_bounds__(256) void gather_nodes(
    const int* __restrict__ src_sorted, const unsigned* __restrict__ offs,
    const float* __restrict__ ws_, const unsigned* __restrict__ zes,
    const float* __restrict__ ed, float* __restrict__ out, int N)
{
    const int lane = threadIdx.x & 63;
    const int g = lane >> 4;
    const int c4 = lane & 15;
    const int d = blockIdx.x * 4 + (threadIdx.x >> 6);
    if (d >= N) return;
    const unsigned o0 = offs[d], o1 = offs[d + 1];
    const int deg = (int)(o1 - o0);

    float az0 = 0.f, az1 = 0.f, az2 = 0.f, az3 = 0.f;
    float ae0 = 0.f, ae1 = 0.f, ae2 = 0.f, ae3 = 0.f;
    float lsum = 0.f;

    for (unsigned o = o0; o < o1; o += 64) {
        const int rem = min(64, (int)(o1 - o));
        int s = 0; float w = 0.f;
        if (lane < rem) { s = src_sorted[o + lane]; w = ws_[s]; }
        lsum += w;
        for (int j = 0; j < rem; j += 4) {
            int s0 = __builtin_amdgcn_readlane(s, j);
            int s1 = __builtin_amdgcn_readlane(s, j + 1);
            int s2 = __builtin_amdgcn_readlane(s, j + 2);
            int s3 = __builtin_amdgcn_readlane(s, j + 3);
            float w0 = __uint_as_float(__builtin_amdgcn_readlane(__float_as_uint(w), j));
            float w1 = __uint_as_float(__builtin_amdgcn_readlane(__float_as_uint(w), j + 1));
            float w2 = __uint_as_float(__builtin_amdgcn_readlane(__float_as_uint(w), j + 2));
            float w3 = __uint_as_float(__builtin_amdgcn_readlane(__float_as_uint(w), j + 3));
            int   sg = (g == 0) ? s0 : ((g == 1) ? s1 : ((g == 2) ? s2 : s3));
            float wg = (g == 0) ? w0 : ((g == 1) ? w1 : ((g == 2) ? w2 : w3));
            const bool valid = (j + g) < rem;          // wg already 0 for invalid
            const uint4 u = *(const uint4*)&zes[(size_t)sg * 64 + c4 * 4];
            float z0 = __uint_as_float(u.x << 16), e0 = __uint_as_float(u.x & 0xffff0000u);
            float z1 = __uint_as_float(u.y << 16), e1 = __uint_as_float(u.y & 0xffff0000u);
            float z2 = __uint_as_float(u.z << 16), e2 = __uint_as_float(u.z & 0xffff0000u);
            float z3 = __uint_as_float(u.w << 16), e3 = __uint_as_float(u.w & 0xffff0000u);
            az0 = fmaf(wg, z0, az0); ae0 += valid ? e0 : 0.f;
            az1 = fmaf(wg, z1, az1); ae1 += valid ? e1 : 0.f;
            az2 = fmaf(wg, z2, az2); ae2 += valid ? e2 : 0.f;
            az3 = fmaf(wg, z3, az3); ae3 += valid ? e3 : 0.f;
        }
    }

    // combine the 4 edge-groups (lanes differing in g, same c4)
    az0 += __shfl_xor(az0, 16); az0 += __shfl_xor(az0, 32);
    az1 += __shfl_xor(az1, 16); az1 += __shfl_xor(az1, 32);
    az2 += __shfl_xor(az2, 16); az2 += __shfl_xor(az2, 32);
    az3 += __shfl_xor(az3, 16); az3 += __shfl_xor(az3, 32);
    ae0 += __shfl_xor(ae0, 16); ae0 += __shfl_xor(ae0, 32);
    ae1 += __shfl_xor(ae1, 16); ae1 += __shfl_xor(ae1, 32);
    ae2 += __shfl_xor(ae2, 16); ae2 += __shfl_xor(ae2, 32);
    ae3 += __shfl_xor(ae3, 16); ae3 += __shfl_xor(ae3, 32);
    #pragma unroll
    for (int off = 32; off; off >>= 1) lsum += __shfl_xor(lsum, off);

    if (g == 0) {
        const float inv = (lsum > 0.f) ? 1.f / lsum : 0.f;
        const float4 edv = *(const float4*)&ed[(size_t)d * 64 + c4 * 4];
        float4 r;
        r.x = fmaf((float)deg, edv.x, fmaf(az0, inv, ae0));
        r.y = fmaf((float)deg, edv.y, fmaf(az1, inv, ae1));
        r.z = fmaf((float)deg, edv.z, fmaf(az2, inv, ae2));
        r.w = fmaf((float)deg, edv.w, fmaf(az3, inv, ae3));
        *(float4*)&out[(size_t)d * 64 + c4 * 4] = r;
    }
}

extern "C" void kernel_launch(void* const* d_in, const int* in_sizes, int n_in,
                              void* d_out, int out_size, void* d_ws, size_t ws_size,
                              hipStream_t stream) {
    const float* h      = (const float*)d_in[0];
    const float* W_fc   = (const float*)d_in[1];
    const float* W_attn = (const float*)d_in[2];
    const float* W_edge = (const float*)d_in[3];
    const int*   src    = (const int*)d_in[4];
    const int*   dst    = (const int*)d_in[5];
    float* out = (float*)d_out;

    const int N = in_sizes[0] / IN_DIM;       // 100000
    const int E = in_sizes[4];                // 1600000

    char* p = (char*)d_ws;
    auto alloc = [&](size_t bytes) -> void* {
        void* r = (void*)p;
        p += (bytes + 255) & ~(size_t)255;
        return r;
    };
    unsigned* zes    = (unsigned*)alloc((size_t)N * 64 * 4);   // packed bf16 (z, es)
    float*    ed     = (float*)alloc((size_t)N * 64 * 4);
    float*    ws_    = (float*)alloc((size_t)N * 4);
    unsigned* deg    = (unsigned*)alloc((size_t)N * 4);
    unsigned* cursor = (unsigned*)alloc((size_t)N * 4);
    unsigned* offs   = (unsigned*)alloc((size_t)(N + 1) * 4);
    unsigned* part   = (unsigned*)alloc((size_t)((N + 255) / 256) * 4);
    int*      src_s  = (int*)alloc((size_t)E * 4);
    float*    W1     = (float*)alloc(128 * 64 * 4);
    float*    W2     = (float*)alloc(128 * 64 * 4);
    unsigned* bfrag  = (unsigned*)alloc((size_t)12 * 4 * 64 * 16);

    hipMemsetAsync(deg, 0, (size_t)N * 4, stream);
    hipMemsetAsync(cursor, 0, (size_t)N * 4, stream);

    precompute_weights<<<128, 64, 0, stream>>>(W_fc, W_edge, W1, W2);
    pack_bfrags<<<12, 256, 0, stream>>>(W_fc, W1, W2, bfrag);

    int blocksA = (N + 63) / 64;
    node_gemm<<<blocksA, 256, 0, stream>>>(h, bfrag, W_attn, zes, ed, ws_, N);

    int blocksE = (E + 255) / 256;
    count_deg<<<blocksE, 256, 0, stream>>>(dst, deg, E);

    int nb = (N + 255) / 256;
    scan_partial<<<nb, 256, 0, stream>>>(deg, part, N);
    scan_blocksums<<<1, 256, 0, stream>>>(part, nb);
    scan_final<<<nb, 256, 0, stream>>>(deg, part, offs, N);

    bin_edges<<<blocksE, 256, 0, stream>>>(src, dst, offs, cursor, src_s, E);

    gather_nodes<<<(N + 3) / 4, 256, 0, stream>>>(src_s, offs, ws_, zes, ed, out, N);
}

// Round 5
// 253.738 us; speedup vs baseline: 3.0772x; 1.3922x over previous
//
#include <hip/hip_runtime.h>

#define IN_DIM 128
#define OUT_DIM 64

#define NB 256        // coarse buckets
#define BSHIFT 9      // bucket = dst >> 9
#define NPB 512       // nodes per bucket
#define EPT 16        // edges per thread in coarse passes

typedef __attribute__((ext_vector_type(8))) short short8;
typedef __attribute__((ext_vector_type(4))) float f32x4;

// ---------- bf16 pack (RNE) ----------
__device__ __forceinline__ unsigned pack_bf16x2(float a, float b) {
    unsigned ua = __float_as_uint(a), ub = __float_as_uint(b);
    ua = (ua + 0x7fffu + ((ua >> 16) & 1u)) >> 16;
    ub = (ub + 0x7fffu + ((ub >> 16) & 1u)) >> 16;
    return ua | (ub << 16);
}

// ---------- kernel P: weight products ----------
__global__ void precompute_weights(const float* __restrict__ W_fc,
                                   const float* __restrict__ W_edge,
                                   float* __restrict__ W1, float* __restrict__ W2) {
    int k = blockIdx.x;    // 0..127
    int j = threadIdx.x;   // 0..63
    __shared__ float row[64];
    row[j] = W_fc[k * 64 + j];
    __syncthreads();
    float s1 = 0.f, s2 = 0.f;
    #pragma unroll 8
    for (int m = 0; m < 64; ++m) {
        float w = row[m];
        s1 = fmaf(w, W_edge[m * 64 + j], s1);
        s2 = fmaf(w, W_edge[(64 + m) * 64 + j], s2);
    }
    W1[k * 64 + j] = s1;
    W2[k * 64 + j] = s2;
}

// ---------- kernel P2: pack B-fragments for MFMA ----------
__global__ void pack_bfrags(const float* __restrict__ W_fc, const float* __restrict__ W1,
                            const float* __restrict__ W2, unsigned* __restrict__ bfrag) {
    int slot = blockIdx.x * 256 + threadIdx.x;       // 0..3071
    if (slot >= 12 * 4 * 64) return;
    int lane = slot & 63;
    int ks = (slot >> 6) & 3;
    int t = slot >> 8;                                // 0..11
    int grp = t >> 2;
    int col = (t & 3) * 16 + (lane & 15);
    int kbase = ks * 32 + (lane >> 4) * 8;
    const float* W = (grp == 0) ? W_fc : ((grp == 1) ? W1 : W2);
    unsigned o0 = pack_bf16x2(W[(kbase + 0) * 64 + col], W[(kbase + 1) * 64 + col]);
    unsigned o1 = pack_bf16x2(W[(kbase + 2) * 64 + col], W[(kbase + 3) * 64 + col]);
    unsigned o2 = pack_bf16x2(W[(kbase + 4) * 64 + col], W[(kbase + 5) * 64 + col]);
    unsigned o3 = pack_bf16x2(W[(kbase + 6) * 64 + col], W[(kbase + 7) * 64 + col]);
    ((uint4*)bfrag)[slot] = make_uint4(o0, o1, o2, o3);
}

// ---------- kernel A: MFMA node GEMM ----------
__global__ __launch_bounds__(256) void node_gemm(
    const float* __restrict__ h, const unsigned* __restrict__ bfrag,
    const float* __restrict__ W_attn,
    unsigned* __restrict__ zes, float* __restrict__ ed,
    float* __restrict__ ws_, int N)
{
    __shared__ uint4 lds4[1024];   // 16 KB: 64 rows x 128 bf16, XOR-swizzled
    char* lds = (char*)lds4;
    const int tid = threadIdx.x;
    const int lane = tid & 63;
    const int w = tid >> 6;
    const int n0 = blockIdx.x * 64;

    #pragma unroll
    for (int r = 0; r < 8; ++r) {
        int idx = r * 256 + tid;
        int row = idx >> 5;
        int c4 = idx & 31;
        float4 v = make_float4(0.f, 0.f, 0.f, 0.f);
        int n = n0 + row;
        if (n < N) v = *(const float4*)(h + (size_t)n * IN_DIM + c4 * 4);
        int byte = (row << 8) + (c4 << 3);
        byte ^= ((row & 7) << 4);
        *(uint2*)(lds + byte) = make_uint2(pack_bf16x2(v.x, v.y), pack_bf16x2(v.z, v.w));
    }
    __syncthreads();

    const int g = lane >> 4;
    const int c = lane & 15;

    union U { uint4 u; short8 s; };
    U a[4];
    {
        const int arow = (w << 4) + c;
        #pragma unroll
        for (int ks = 0; ks < 4; ++ks) {
            int byte = (arow << 8) + (ks << 6) + (g << 4);
            byte ^= ((arow & 7) << 4);
            a[ks].u = *(const uint4*)(lds + byte);
        }
    }

    f32x4 acc[12];
    #pragma unroll
    for (int t = 0; t < 12; ++t) acc[t] = (f32x4){0.f, 0.f, 0.f, 0.f};

    const uint4* bf4 = (const uint4*)bfrag;
    #pragma unroll
    for (int t = 0; t < 12; ++t) {
        #pragma unroll
        for (int ks = 0; ks < 4; ++ks) {
            U b; b.u = bf4[(t * 4 + ks) * 64 + lane];
            acc[t] = __builtin_amdgcn_mfma_f32_16x16x32_bf16(a[ks].s, b.s, acc[t], 0, 0, 0);
        }
    }

    const float wa0 = W_attn[c], wa1 = W_attn[16 + c], wa2 = W_attn[32 + c], wa3 = W_attn[48 + c];
    #pragma unroll
    for (int r = 0; r < 4; ++r) {
        const int n = n0 + (w << 4) + (g << 2) + r;
        float part = acc[0][r] * wa0 + acc[1][r] * wa1 + acc[2][r] * wa2 + acc[3][r] * wa3;
        part += __shfl_xor(part, 1);
        part += __shfl_xor(part, 2);
        part += __shfl_xor(part, 4);
        part += __shfl_xor(part, 8);
        if (n < N) {
            #pragma unroll
            for (int t = 0; t < 4; ++t) {
                const int col = t * 16 + c;
                zes[(size_t)n * 64 + col] = pack_bf16x2(acc[t][r], acc[t + 4][r]);
                ed [(size_t)n * 64 + col] = acc[t + 8][r];
            }
            if (c == 0) ws_[n] = expf(part);
        }
    }
}

// ---------- CSR build v2: bucketed two-level counting sort ----------
// pass A: 256-bucket histogram (LDS-aggregated)
__global__ __launch_bounds__(256) void coarse_hist(const int* __restrict__ dst,
                                                   unsigned* __restrict__ hist, int E) {
    __shared__ unsigned hl[NB];
    const int t = threadIdx.x;
    hl[t] = 0;
    __syncthreads();
    const int base = blockIdx.x * (256 * EPT);
    const int lim = min(base + 256 * EPT, E);
    for (int i = base + t; i < lim; i += 256)
        atomicAdd(&hl[((unsigned)dst[i]) >> BSHIFT], 1u);
    __syncthreads();
    if (hl[t]) atomicAdd(&hist[t], hl[t]);
}

// pass A2 (1 block): exclusive scan -> bucketBase[0..NB], cursor init
__global__ void bucket_scan(const unsigned* __restrict__ hist,
                            unsigned* __restrict__ bucketBase, unsigned* __restrict__ cursor) {
    __shared__ unsigned s[NB];
    const int t = threadIdx.x;
    unsigned v = hist[t];
    s[t] = v; __syncthreads();
    for (int off = 1; off < NB; off <<= 1) {
        unsigned add = (t >= off) ? s[t - off] : 0u;
        __syncthreads();
        s[t] += add;
        __syncthreads();
    }
    unsigned excl = s[t] - v;
    bucketBase[t] = excl;
    cursor[t] = excl;
    if (t == NB - 1) bucketBase[NB] = s[t];
}

// pass B: scatter (src, dstLocal) grouped by coarse bucket; per-(block,bucket)
// contiguous ranges reserved with ONE global atomic each -> sequential streams.
__global__ __launch_bounds__(256) void coarse_scatter(
    const int* __restrict__ src, const int* __restrict__ dst,
    unsigned* __restrict__ cursor, uint2* __restrict__ pairs, int E)
{
    __shared__ unsigned h[NB];
    __shared__ unsigned start[NB];
    const int t = threadIdx.x;
    h[t] = 0;
    __syncthreads();
    const int base = blockIdx.x * (256 * EPT);
    unsigned sv[EPT], dv[EPT], rk[EPT];
    #pragma unroll
    for (int k = 0; k < EPT; ++k) {
        int i = base + k * 256 + t;
        bool valid = i < E;
        unsigned s = 0, d = 0;
        if (valid) { s = (unsigned)src[i]; d = (unsigned)dst[i]; }
        sv[k] = s;
        dv[k] = valid ? d : 0xFFFFFFFFu;
        rk[k] = valid ? atomicAdd(&h[d >> BSHIFT], 1u) : 0u;
    }
    __syncthreads();
    start[t] = h[t] ? atomicAdd(&cursor[t], h[t]) : 0u;
    __syncthreads();
    #pragma unroll
    for (int k = 0; k < EPT; ++k) {
        if (dv[k] != 0xFFFFFFFFu) {
            unsigned b = dv[k] >> BSHIFT;
            pairs[start[b] + rk[k]] = make_uint2(sv[k], dv[k] & (NPB - 1));
        }
    }
}

// pass C: one block per bucket — local deg, LDS scan -> global offs, rank-scatter src
__global__ __launch_bounds__(256) void fine_bin(
    const uint2* __restrict__ pairs, const unsigned* __restrict__ bucketBase,
    unsigned* __restrict__ offs, int* __restrict__ src_sorted, int N, int E)
{
    __shared__ unsigned deg[NPB];
    __shared__ unsigned excl[NPB];
    __shared__ unsigned pscan[256];
    const int b = blockIdx.x;
    const int t = threadIdx.x;
    const int node0 = b << BSHIFT;
    const unsigned e0 = bucketBase[b], e1 = bucketBase[b + 1];

    deg[t] = 0; deg[t + 256] = 0;
    __syncthreads();
    for (unsigned i = e0 + t; i < e1; i += 256)
        atomicAdd(&deg[pairs[i].y], 1u);
    __syncthreads();

    // exclusive scan of 512 via 256-wide pair scan
    unsigned a0 = deg[2 * t], a1 = deg[2 * t + 1];
    unsigned ps = a0 + a1;
    pscan[t] = ps;
    __syncthreads();
    for (int off = 1; off < 256; off <<= 1) {
        unsigned add = (t >= off) ? pscan[t - off] : 0u;
        __syncthreads();
        pscan[t] += add;
        __syncthreads();
    }
    unsigned exclP = pscan[t] - ps;
    excl[2 * t] = exclP;
    excl[2 * t + 1] = exclP + a0;
    __syncthreads();

    #pragma unroll
    for (int l = t; l < NPB; l += 256) {
        int n = node0 + l;
        if (n < N) offs[n] = e0 + excl[l];
    }
    if (b == 0 && t == 0) offs[N] = (unsigned)E;
    __syncthreads();

    for (unsigned i = e0 + t; i < e1; i += 256) {
        uint2 p = pairs[i];
        unsigned pos = e0 + atomicAdd(&excl[p.y], 1u);
        src_sorted[pos] = (int)p.x;
    }
}

// ---------- kernel G: per-dst gather, 4 edges in flight ----------
__global__ __launch_bounds__(256) void gather_nodes(
    const int* __restrict__ src_sorted, const unsigned* __restrict__ offs,
    const float* __restrict__ ws_, const unsigned* __restrict__ zes,
    const float* __restrict__ ed, float* __restrict__ out, int N)
{
    const int lane = threadIdx.x & 63;
    const int g = lane >> 4;
    const int c4 = lane & 15;
    const int d = blockIdx.x * 4 + (threadIdx.x >> 6);
    if (d >= N) return;
    const unsigned o0 = offs[d], o1 = offs[d + 1];
    const int deg = (int)(o1 - o0);

    float az0 = 0.f, az1 = 0.f, az2 = 0.f, az3 = 0.f;
    float ae0 = 0.f, ae1 = 0.f, ae2 = 0.f, ae3 = 0.f;
    float lsum = 0.f;

    for (unsigned o = o0; o < o1; o += 64) {
        const int rem = min(64, (int)(o1 - o));
        int s = 0; float w = 0.f;
        if (lane < rem) { s = src_sorted[o + lane]; w = ws_[s]; }
        lsum += w;
        for (int j = 0; j < rem; j += 4) {
            int s0 = __builtin_amdgcn_readlane(s, j);
            int s1 = __builtin_amdgcn_readlane(s, j + 1);
            int s2 = __builtin_amdgcn_readlane(s, j + 2);
            int s3 = __builtin_amdgcn_readlane(s, j + 3);
            float w0 = __uint_as_float(__builtin_amdgcn_readlane(__float_as_uint(w), j));
            float w1 = __uint_as_float(__builtin_amdgcn_readlane(__float_as_uint(w), j + 1));
            float w2 = __uint_as_float(__builtin_amdgcn_readlane(__float_as_uint(w), j + 2));
            float w3 = __uint_as_float(__builtin_amdgcn_readlane(__float_as_uint(w), j + 3));
            int   sg = (g == 0) ? s0 : ((g == 1) ? s1 : ((g == 2) ? s2 : s3));
            float wg = (g == 0) ? w0 : ((g == 1) ? w1 : ((g == 2) ? w2 : w3));
            const bool valid = (j + g) < rem;
            const uint4 u = *(const uint4*)&zes[(size_t)sg * 64 + c4 * 4];
            float z0 = __uint_as_float(u.x << 16), e0 = __uint_as_float(u.x & 0xffff0000u);
            float z1 = __uint_as_float(u.y << 16), e1 = __uint_as_float(u.y & 0xffff0000u);
            float z2 = __uint_as_float(u.z << 16), e2 = __uint_as_float(u.z & 0xffff0000u);
            float z3 = __uint_as_float(u.w << 16), e3 = __uint_as_float(u.w & 0xffff0000u);
            az0 = fmaf(wg, z0, az0); ae0 += valid ? e0 : 0.f;
            az1 = fmaf(wg, z1, az1); ae1 += valid ? e1 : 0.f;
            az2 = fmaf(wg, z2, az2); ae2 += valid ? e2 : 0.f;
            az3 = fmaf(wg, z3, az3); ae3 += valid ? e3 : 0.f;
        }
    }

    az0 += __shfl_xor(az0, 16); az0 += __shfl_xor(az0, 32);
    az1 += __shfl_xor(az1, 16); az1 += __shfl_xor(az1, 32);
    az2 += __shfl_xor(az2, 16); az2 += __shfl_xor(az2, 32);
    az3 += __shfl_xor(az3, 16); az3 += __shfl_xor(az3, 32);
    ae0 += __shfl_xor(ae0, 16); ae0 += __shfl_xor(ae0, 32);
    ae1 += __shfl_xor(ae1, 16); ae1 += __shfl_xor(ae1, 32);
    ae2 += __shfl_xor(ae2, 16); ae2 += __shfl_xor(ae2, 32);
    ae3 += __shfl_xor(ae3, 16); ae3 += __shfl_xor(ae3, 32);
    #pragma unroll
    for (int off = 32; off; off >>= 1) lsum += __shfl_xor(lsum, off);

    if (g == 0) {
        const float inv = (lsum > 0.f) ? 1.f / lsum : 0.f;
        const float4 edv = *(const float4*)&ed[(size_t)d * 64 + c4 * 4];
        float4 r;
        r.x = fmaf((float)deg, edv.x, fmaf(az0, inv, ae0));
        r.y = fmaf((float)deg, edv.y, fmaf(az1, inv, ae1));
        r.z = fmaf((float)deg, edv.z, fmaf(az2, inv, ae2));
        r.w = fmaf((float)deg, edv.w, fmaf(az3, inv, ae3));
        *(float4*)&out[(size_t)d * 64 + c4 * 4] = r;
    }
}

extern "C" void kernel_launch(void* const* d_in, const int* in_sizes, int n_in,
                              void* d_out, int out_size, void* d_ws, size_t ws_size,
                              hipStream_t stream) {
    const float* h      = (const float*)d_in[0];
    const float* W_fc   = (const float*)d_in[1];
    const float* W_attn = (const float*)d_in[2];
    const float* W_edge = (const float*)d_in[3];
    const int*   src    = (const int*)d_in[4];
    const int*   dst    = (const int*)d_in[5];
    float* out = (float*)d_out;

    const int N = in_sizes[0] / IN_DIM;       // 100000
    const int E = in_sizes[4];                // 1600000

    char* p = (char*)d_ws;
    auto alloc = [&](size_t bytes) -> void* {
        void* r = (void*)p;
        p += (bytes + 255) & ~(size_t)255;
        return r;
    };
    unsigned* zes    = (unsigned*)alloc((size_t)N * 64 * 4);   // packed bf16 (z, es)
    float*    ed     = (float*)alloc((size_t)N * 64 * 4);
    float*    ws_    = (float*)alloc((size_t)N * 4);
    unsigned* offs   = (unsigned*)alloc((size_t)(N + 1) * 4);
    unsigned* hist   = (unsigned*)alloc(NB * 4);
    unsigned* bbase  = (unsigned*)alloc((NB + 1) * 4);
    unsigned* cursor = (unsigned*)alloc(NB * 4);
    uint2*    pairs  = (uint2*)alloc((size_t)E * 8);
    int*      src_s  = (int*)alloc((size_t)E * 4);
    float*    W1     = (float*)alloc(128 * 64 * 4);
    float*    W2     = (float*)alloc(128 * 64 * 4);
    unsigned* bfrag  = (unsigned*)alloc((size_t)12 * 4 * 64 * 16);

    hipMemsetAsync(hist, 0, NB * 4, stream);

    precompute_weights<<<128, 64, 0, stream>>>(W_fc, W_edge, W1, W2);
    pack_bfrags<<<12, 256, 0, stream>>>(W_fc, W1, W2, bfrag);

    int blocksA = (N + 63) / 64;
    node_gemm<<<blocksA, 256, 0, stream>>>(h, bfrag, W_attn, zes, ed, ws_, N);

    int blocksC = (E + 256 * EPT - 1) / (256 * EPT);
    coarse_hist<<<blocksC, 256, 0, stream>>>(dst, hist, E);
    bucket_scan<<<1, NB, 0, stream>>>(hist, bbase, cursor);
    coarse_scatter<<<blocksC, 256, 0, stream>>>(src, dst, cursor, pairs, E);
    fine_bin<<<NB, 256, 0, stream>>>(pairs, bbase, offs, src_s, N, E);

    gather_nodes<<<(N + 3) / 4, 256, 0, stream>>>(src_s, offs, ws_, zes, ed, out, N);
}